// Round 1
// baseline (1398.790 us; speedup 1.0000x reference)
//
#include <hip/hip_runtime.h>
#include <math.h>

#define BB 128
#define MM 35
#define PSZ 224
#define PP (PSZ*PSZ)          // 50176
#define NIMG (2*BB)           // 256 images (focus + defocus)
#define SIGN_PENALTY 10.0f
#define RECON_WEIGHT 0.4f
#define DEFOCUS_RAD 1.0f
#define EPS_F 1e-8f
#define TWO_PI_F 6.2831853071795864769f

// ws layout (floats):
//   [0]            sum(mask^2)
//   [1]            z_loss
//   [16 .. 16+1792) stage2 block partials (7*128*2 blocks)
//   [2048 ..)      phase  [B][P][P]            (6,422,528 floats)
//   [T_OFF ..)     T      [2][B][P][P] complex (25,690,112 floats)
#define WS_PARTIALS_OFF 16
#define WS_PHASE_OFF    2048
#define WS_T_OFF        (WS_PHASE_OFF + BB*PP)
#define N_PARTIALS      (7*BB*2)

__device__ __forceinline__ float lincoord(int i) {
    return -1.0f + 2.0f * (float)i / (float)(PSZ - 1);
}

// ---------------- z_loss: sign-weighted MSE over [B,M] ----------------
__global__ void k_zloss(const float* __restrict__ pred,
                        const float* __restrict__ target,
                        float* __restrict__ ws) {
    __shared__ float red[256];
    float s = 0.f;
    for (int i = threadIdx.x; i < BB * MM; i += 256) {
        float p = pred[i], t = target[i];
        float d = p - t;
        float w = (p * t < 0.f) ? SIGN_PENALTY : 1.f;
        s = fmaf(d * d, w, s);
    }
    red[threadIdx.x] = s;
    __syncthreads();
    for (int st = 128; st > 0; st >>= 1) {
        if (threadIdx.x < st) red[threadIdx.x] += red[threadIdx.x + st];
        __syncthreads();
    }
    if (threadIdx.x == 0) ws[1] = red[0] / (float)(BB * MM);
}

// ---------------- sum(mask^2) for Parseval denominator ----------------
__global__ void k_mask2(const float* __restrict__ mask, float* __restrict__ ws) {
    __shared__ float red[256];
    float s = 0.f;
    for (int i = threadIdx.x; i < PP; i += 256) {
        float m = mask[i];
        s = fmaf(m, m, s);
    }
    red[threadIdx.x] = s;
    __syncthreads();
    for (int st = 128; st > 0; st >>= 1) {
        if (threadIdx.x < st) red[threadIdx.x] += red[threadIdx.x + st];
        __syncthreads();
    }
    if (threadIdx.x == 0) ws[0] = red[0];
}

// ---------------- phase[b,pix] = (sum_m pred[b,m] * Z[m,pix]) * mask[pix] --
// grid: (196, 8) — x covers pixels (196*256 == 50176), y = b-group of 16
__global__ __launch_bounds__(256) void k_phase(const float* __restrict__ pred,
                                               const float* __restrict__ zern,
                                               const float* __restrict__ mask,
                                               float* __restrict__ phase) {
    __shared__ float pl[16 * MM];
    int bg = blockIdx.y;
    for (int i = threadIdx.x; i < 16 * MM; i += 256) {
        int j = i / MM, m = i % MM;
        pl[i] = pred[(bg * 16 + j) * MM + m];
    }
    __syncthreads();
    int pix = blockIdx.x * 256 + threadIdx.x;   // always < PP (196*256==PP)
    float acc[16];
#pragma unroll
    for (int j = 0; j < 16; j++) acc[j] = 0.f;
    for (int m = 0; m < MM; m++) {
        float z = zern[m * PP + pix];
#pragma unroll
        for (int j = 0; j < 16; j++) acc[j] = fmaf(pl[j * MM + m], z, acc[j]);
    }
    float mk = mask[pix];
#pragma unroll
    for (int j = 0; j < 16; j++) phase[(size_t)(bg * 16 + j) * PP + pix] = acc[j] * mk;
}

// ---------------- stage 1: row DFT (over w) of pupil = mask*exp(i(phase+def))
// grid: (P, B, 2); block 256 (224 active outputs k2 = tid)
__global__ __launch_bounds__(256) void k_stage1(const float* __restrict__ phase,
                                                const float* __restrict__ mask,
                                                float2* __restrict__ T) {
    __shared__ float pr[PSZ], pi[PSZ];
    int h = blockIdx.x, b = blockIdx.y, d = blockIdx.z;
    int t = threadIdx.x;
    if (t < PSZ) {
        float ph = phase[(size_t)b * PP + h * PSZ + t];
        if (d) {
            float vy = lincoord(h), vx = lincoord(t);
            ph += DEFOCUS_RAD * (2.f * (vx * vx + vy * vy) - 1.f);
        }
        float mk = mask[h * PSZ + t];
        float sn, cs;
        sincosf(ph, &sn, &cs);
        pr[t] = mk * cs;
        pi[t] = mk * sn;
    }
    __syncthreads();
    if (t >= PSZ) return;
    // out[k2=t] = sum_w pupil[w] * exp(-2pi i * t * w / P), via rotation recurrence
    float sa, ca;
    sincosf(-TWO_PI_F * (float)t / (float)PSZ, &sa, &ca);
    float ar = 0.f, ai = 0.f, cr = 1.f, ci = 0.f;
    for (int w = 0; w < PSZ; ++w) {
        float xr = pr[w], xi = pi[w];
        ar = fmaf(cr, xr, ar); ar = fmaf(-ci, xi, ar);
        ai = fmaf(cr, xi, ai); ai = fmaf(ci, xr, ai);
        float nr = fmaf(cr, ca, -ci * sa);
        float nc = fmaf(cr, sa,  ci * ca);
        cr = nr; ci = nc;
    }
    int img = d * BB + b;
    T[((size_t)img * PSZ + h) * PSZ + t] = make_float2(ar, ai);
}

// ---------------- stage 2: column DFT (over h) + |Y|^2/denom vs input psf ----
// grid: (7, B, 2); block 256. LDS tile: T[all h][32 k2 cols]
__global__ __launch_bounds__(256) void k_stage2(const float2* __restrict__ T,
                                                const float* __restrict__ psfs,
                                                const float* __restrict__ ws,
                                                float* __restrict__ partials) {
    __shared__ float2 Ts[PSZ][32];   // 57344 B
    __shared__ float red[256];
    int tile = blockIdx.x, b = blockIdx.y, d = blockIdx.z;
    int img = d * BB + b;
    int t = threadIdx.x;
    for (int i = t; i < PSZ * 32; i += 256) {
        int h = i >> 5, c = i & 31;
        Ts[h][c] = T[((size_t)img * PSZ + h) * PSZ + tile * 32 + c];
    }
    __syncthreads();
    float denom = ws[0] * (float)PP + EPS_F;   // Parseval: sum(psf_raw) = P^2 * sum(mask^2)
    float inv_denom = 1.f / denom;
    int col = t & 31;
    int grp = t >> 5;                  // 8 groups x 28 k1 each = 224
    int k2 = tile * 32 + col;
    int sk2 = (k2 + PSZ / 2) % PSZ;
    const float* inp = psfs + ((size_t)b * 2 + d) * PP;
    float lsum = 0.f;
    for (int j = 0; j < 28; ++j) {
        int k1 = grp * 28 + j;
        float sa, ca;
        sincosf(-TWO_PI_F * (float)k1 / (float)PSZ, &sa, &ca);
        float ar = 0.f, ai = 0.f, cr = 1.f, ci = 0.f;
        for (int h = 0; h < PSZ; ++h) {
            float2 x = Ts[h][col];
            ar = fmaf(cr, x.x, ar); ar = fmaf(-ci, x.y, ar);
            ai = fmaf(cr, x.y, ai); ai = fmaf(ci, x.x, ai);
            float nr = fmaf(cr, ca, -ci * sa);
            float nc = fmaf(cr, sa,  ci * ca);
            cr = nr; ci = nc;
        }
        float psf = (ar * ar + ai * ai) * inv_denom;
        int sk1 = (k1 + PSZ / 2) % PSZ;
        float diff = psf - inp[sk1 * PSZ + sk2];
        lsum = fmaf(diff, diff, lsum);
    }
    red[t] = lsum;
    __syncthreads();
    for (int st = 128; st > 0; st >>= 1) {
        if (t < st) red[t] += red[t + st];
        __syncthreads();
    }
    if (t == 0)
        partials[(blockIdx.z * gridDim.y + blockIdx.y) * gridDim.x + blockIdx.x] = red[0];
}

// ---------------- final: combine ----------------
__global__ void k_final(const float* __restrict__ ws,
                        const float* __restrict__ partials,
                        float* __restrict__ out) {
    __shared__ float red[256];
    float s = 0.f;
    for (int i = threadIdx.x; i < N_PARTIALS; i += 256) s += partials[i];
    red[threadIdx.x] = s;
    __syncthreads();
    for (int st = 128; st > 0; st >>= 1) {
        if (threadIdx.x < st) red[threadIdx.x] += red[threadIdx.x + st];
        __syncthreads();
    }
    if (threadIdx.x == 0) {
        float recon = red[0] / (float)((size_t)BB * PP);  // sum of both means' numerators
        out[0] = ws[1] + RECON_WEIGHT * recon;
    }
}

extern "C" void kernel_launch(void* const* d_in, const int* in_sizes, int n_in,
                              void* d_out, int out_size, void* d_ws, size_t ws_size,
                              hipStream_t stream) {
    const float* pred   = (const float*)d_in[0];
    const float* target = (const float*)d_in[1];
    const float* psfs   = (const float*)d_in[2];
    const float* zern   = (const float*)d_in[3];
    const float* mask   = (const float*)d_in[4];

    float*  ws       = (float*)d_ws;
    float*  partials = ws + WS_PARTIALS_OFF;
    float*  phase    = ws + WS_PHASE_OFF;
    float2* T        = (float2*)(ws + WS_T_OFF);
    float*  out      = (float*)d_out;

    k_zloss<<<1, 256, 0, stream>>>(pred, target, ws);
    k_mask2<<<1, 256, 0, stream>>>(mask, ws);
    k_phase<<<dim3(PP / 256, BB / 16), 256, 0, stream>>>(pred, zern, mask, phase);
    k_stage1<<<dim3(PSZ, BB, 2), 256, 0, stream>>>(phase, mask, T);
    k_stage2<<<dim3(7, BB, 2), 256, 0, stream>>>(T, psfs, ws, partials);
    k_final<<<1, 256, 0, stream>>>(ws, partials, out);
}

// Round 2
// 377.344 us; speedup vs baseline: 3.7069x; 3.7069x over previous
//
#include <hip/hip_runtime.h>
#include <math.h>

#define BB 128
#define MM 35
#define PSZ 224
#define PP (PSZ*PSZ)          // 50176
#define SIGN_PENALTY 10.0f
#define RECON_WEIGHT 0.4f
#define DEFOCUS_RAD 1.0f
#define EPS_F 1e-8f
#define TWO_PI_F 6.2831853071795864769f

// CT factorization: 224 = 14*16.  n = 14*n2 + n1 (n1<14, n2<16); k = 16*k1 + k2.
// X[16k1+k2] = sum_n1 W14[n1*k1] * Wtw(n1*k2/224) * [ sum_n2 x[14n2+n1] * W16[n2*k2] ]

// ws layout (floats):
//   [0] sum(mask^2)   [1] z_loss
//   [2048 ..) phase [B][P][P]  (6.4M floats) — dead after stage1; partials alias it
//   [T_OFF ..) T [2][B][P][P] complex
#define WS_PHASE_OFF    2048
#define WS_T_OFF        (WS_PHASE_OFF + BB*PP)
#define N_PARTIALS      (14*BB*2)

static constexpr float W16R[16] = {
    1.0f, 0.9238795325f, 0.7071067812f, 0.3826834324f, 0.0f,
    -0.3826834324f, -0.7071067812f, -0.9238795325f, -1.0f,
    -0.9238795325f, -0.7071067812f, -0.3826834324f, 0.0f,
    0.3826834324f, 0.7071067812f, 0.9238795325f};
static constexpr float W16I[16] = {
    0.0f, -0.3826834324f, -0.7071067812f, -0.9238795325f, -1.0f,
    -0.9238795325f, -0.7071067812f, -0.3826834324f, 0.0f,
    0.3826834324f, 0.7071067812f, 0.9238795325f, 1.0f,
    0.9238795325f, 0.7071067812f, 0.3826834324f};
static constexpr float W14R[14] = {
    1.0f, 0.9009688679f, 0.6234898019f, 0.2225209340f, -0.2225209340f,
    -0.6234898019f, -0.9009688679f, -1.0f, -0.9009688679f,
    -0.6234898019f, -0.2225209340f, 0.2225209340f, 0.6234898019f,
    0.9009688679f};
static constexpr float W14I[14] = {
    0.0f, -0.4338837391f, -0.7818314825f, -0.9749279122f, -0.9749279122f,
    -0.7818314825f, -0.4338837391f, 0.0f, 0.4338837391f,
    0.7818314825f, 0.9749279122f, 0.9749279122f, 0.7818314825f,
    0.4338837391f};

__device__ __forceinline__ float lincoord(int i) {
    return -1.0f + 2.0f * (float)i / (float)(PSZ - 1);
}

// ---------------- z_loss ----------------
__global__ void k_zloss(const float* __restrict__ pred,
                        const float* __restrict__ target,
                        float* __restrict__ ws) {
    __shared__ float red[256];
    float s = 0.f;
    for (int i = threadIdx.x; i < BB * MM; i += 256) {
        float p = pred[i], t = target[i];
        float d = p - t;
        float w = (p * t < 0.f) ? SIGN_PENALTY : 1.f;
        s = fmaf(d * d, w, s);
    }
    red[threadIdx.x] = s;
    __syncthreads();
    for (int st = 128; st > 0; st >>= 1) {
        if (threadIdx.x < st) red[threadIdx.x] += red[threadIdx.x + st];
        __syncthreads();
    }
    if (threadIdx.x == 0) ws[1] = red[0] / (float)(BB * MM);
}

// ---------------- sum(mask^2) ----------------
__global__ void k_mask2(const float* __restrict__ mask, float* __restrict__ ws) {
    __shared__ float red[256];
    float s = 0.f;
    for (int i = threadIdx.x; i < PP; i += 256) {
        float m = mask[i];
        s = fmaf(m, m, s);
    }
    red[threadIdx.x] = s;
    __syncthreads();
    for (int st = 128; st > 0; st >>= 1) {
        if (threadIdx.x < st) red[threadIdx.x] += red[threadIdx.x + st];
        __syncthreads();
    }
    if (threadIdx.x == 0) ws[0] = red[0];
}

// ---------------- phase = (pred @ zern) * mask ----------------
__global__ __launch_bounds__(256) void k_phase(const float* __restrict__ pred,
                                               const float* __restrict__ zern,
                                               const float* __restrict__ mask,
                                               float* __restrict__ phase) {
    __shared__ float pl[16 * MM];
    int bg = blockIdx.y;
    for (int i = threadIdx.x; i < 16 * MM; i += 256) {
        int j = i / MM, m = i % MM;
        pl[i] = pred[(bg * 16 + j) * MM + m];
    }
    __syncthreads();
    int pix = blockIdx.x * 256 + threadIdx.x;
    float acc[16];
#pragma unroll
    for (int j = 0; j < 16; j++) acc[j] = 0.f;
    for (int m = 0; m < MM; m++) {
        float z = zern[m * PP + pix];
#pragma unroll
        for (int j = 0; j < 16; j++) acc[j] = fmaf(pl[j * MM + m], z, acc[j]);
    }
    float mk = mask[pix];
#pragma unroll
    for (int j = 0; j < 16; j++) phase[(size_t)(bg * 16 + j) * PP + pix] = acc[j] * mk;
}

// ---------------- stage 1: row DFTs via CT 14x16 ----------------
// grid (14, B, 2): block handles 16 h-rows of one image. block = 256.
// LDS: xs [16 rows][225 complex], B1 [16 rows][225 complex]
__global__ __launch_bounds__(256) void k_stage1(const float* __restrict__ phase,
                                                const float* __restrict__ mask,
                                                float2* __restrict__ T) {
    __shared__ float lds[2 * 16 * 450];
    float* xs = lds;
    float* Bb = lds + 16 * 450;
    int h0 = blockIdx.x * 16;
    int b = blockIdx.y, d = blockIdx.z;
    int t = threadIdx.x;

    const float* ph_base = phase + (size_t)b * PP + (size_t)h0 * PSZ;
    for (int idx = t; idx < 16 * PSZ; idx += 256) {
        int r = idx / PSZ, w = idx - r * PSZ;
        float ph = ph_base[r * PSZ + w];
        if (d) {
            float vy = lincoord(h0 + r), vx = lincoord(w);
            ph += DEFOCUS_RAD * (2.f * (vx * vx + vy * vy) - 1.f);
        }
        float mk = mask[(h0 + r) * PSZ + w];
        float sn, cs;
        sincosf(ph, &sn, &cs);
        xs[r * 450 + 2 * w]     = mk * cs;
        xs[r * 450 + 2 * w + 1] = mk * sn;
    }
    __syncthreads();

    if (t < 224) {
        int r = t / 14, n1 = t - r * 14;
        const float2* xr = (const float2*)(xs + r * 450);
        float2 x[16];
#pragma unroll
        for (int n2 = 0; n2 < 16; n2++) x[n2] = xr[14 * n2 + n1];
        float stw_s, stw_c;
        sincosf(-TWO_PI_F * (float)n1 / 224.f, &stw_s, &stw_c);
        float twc = 1.f, tws = 0.f;
        float2* Br = (float2*)(Bb + r * 450);
#pragma unroll
        for (int k2 = 0; k2 < 16; k2++) {
            float ar = 0.f, ai = 0.f;
#pragma unroll
            for (int n2 = 0; n2 < 16; n2++) {
                const float wr = W16R[(n2 * k2) & 15], wi = W16I[(n2 * k2) & 15];
                ar = fmaf(x[n2].x, wr, ar); ar = fmaf(-x[n2].y, wi, ar);
                ai = fmaf(x[n2].x, wi, ai); ai = fmaf(x[n2].y, wr, ai);
            }
            float br = ar * twc - ai * tws;
            float bi = ar * tws + ai * twc;
            Br[k2 * 14 + n1] = make_float2(br, bi);
            float ntc = fmaf(twc, stw_c, -tws * stw_s);
            float nts = fmaf(twc, stw_s,  tws * stw_c);
            twc = ntc; tws = nts;
        }
    }
    __syncthreads();

    {
        int r = t >> 4, k2 = t & 15;
        const float2* Br = (const float2*)(Bb + r * 450);
        float2 Bt[14];
#pragma unroll
        for (int n1 = 0; n1 < 14; n1++) Bt[n1] = Br[k2 * 14 + n1];
        int img = d * BB + b;
        float2* Trow = T + ((size_t)img * PSZ + (h0 + r)) * PSZ;
#pragma unroll
        for (int k1 = 0; k1 < 14; k1++) {
            float ar = 0.f, ai = 0.f;
#pragma unroll
            for (int n1 = 0; n1 < 14; n1++) {
                const float wr = W14R[(n1 * k1) % 14], wi = W14I[(n1 * k1) % 14];
                ar = fmaf(Bt[n1].x, wr, ar); ar = fmaf(-Bt[n1].y, wi, ar);
                ai = fmaf(Bt[n1].x, wi, ai); ai = fmaf(Bt[n1].y, wr, ai);
            }
            Trow[16 * k1 + k2] = make_float2(ar, ai);
        }
    }
}

// ---------------- stage 2: column DFTs via CT 14x16 + psf + loss ----------------
// grid (14, B, 2): block handles 16 columns of one image.
// LDS: xs [224 h][16 cols complex, stride 34 floats] (30464B),
//      B2 [16 cols][225 complex stride 450]          (28800B),
//      psf [224][17] floats aliases xs               (15232B)
__global__ __launch_bounds__(256) void k_stage2(const float2* __restrict__ T,
                                                const float* __restrict__ psfs,
                                                const float* __restrict__ ws,
                                                float* __restrict__ partials) {
    __shared__ float lds[7616 + 7200];
    __shared__ float red[256];
    float* xs  = lds;
    float* Bb  = lds + 7616;
    float* psf = lds;   // aliases xs (dead after inner phase)
    int tile = blockIdx.x, b = blockIdx.y, d = blockIdx.z;
    int img = d * BB + b;
    int col0 = tile * 16;
    int t = threadIdx.x;

    const float2* Tbase = T + (size_t)img * PP + col0;
    for (int idx = t; idx < 224 * 16; idx += 256) {
        int h = idx >> 4, c = idx & 15;
        float2 v = Tbase[(size_t)h * PSZ + c];
        xs[h * 34 + 2 * c]     = v.x;
        xs[h * 34 + 2 * c + 1] = v.y;
    }
    __syncthreads();

    if (t < 224) {
        int n1 = t >> 4, c = t & 15;
        float2 x[16];
#pragma unroll
        for (int n2 = 0; n2 < 16; n2++) {
            int h = 14 * n2 + n1;
            x[n2] = make_float2(xs[h * 34 + 2 * c], xs[h * 34 + 2 * c + 1]);
        }
        float stw_s, stw_c;
        sincosf(-TWO_PI_F * (float)n1 / 224.f, &stw_s, &stw_c);
        float twc = 1.f, tws = 0.f;
        float2* Bc = (float2*)(Bb + c * 450);
#pragma unroll
        for (int k2 = 0; k2 < 16; k2++) {
            float ar = 0.f, ai = 0.f;
#pragma unroll
            for (int n2 = 0; n2 < 16; n2++) {
                const float wr = W16R[(n2 * k2) & 15], wi = W16I[(n2 * k2) & 15];
                ar = fmaf(x[n2].x, wr, ar); ar = fmaf(-x[n2].y, wi, ar);
                ai = fmaf(x[n2].x, wi, ai); ai = fmaf(x[n2].y, wr, ai);
            }
            float br = ar * twc - ai * tws;
            float bi = ar * tws + ai * twc;
            Bc[k2 * 14 + n1] = make_float2(br, bi);
            float ntc = fmaf(twc, stw_c, -tws * stw_s);
            float nts = fmaf(twc, stw_s,  tws * stw_c);
            twc = ntc; tws = nts;
        }
    }
    __syncthreads();

    float denom = ws[0] * (float)PP + EPS_F;   // Parseval
    float inv_denom = 1.f / denom;
    {
        int k2 = t >> 4, c = t & 15;
        const float2* Bc = (const float2*)(Bb + c * 450);
        float2 Bt[14];
#pragma unroll
        for (int n1 = 0; n1 < 14; n1++) Bt[n1] = Bc[k2 * 14 + n1];
#pragma unroll
        for (int k1 = 0; k1 < 14; k1++) {
            float ar = 0.f, ai = 0.f;
#pragma unroll
            for (int n1 = 0; n1 < 14; n1++) {
                const float wr = W14R[(n1 * k1) % 14], wi = W14I[(n1 * k1) % 14];
                ar = fmaf(Bt[n1].x, wr, ar); ar = fmaf(-Bt[n1].y, wi, ar);
                ai = fmaf(Bt[n1].x, wi, ai); ai = fmaf(Bt[n1].y, wr, ai);
            }
            int kh = 16 * k1 + k2;
            psf[kh * 17 + c] = fmaf(ar, ar, ai * ai) * inv_denom;
        }
    }
    __syncthreads();

    int scol0 = 16 * ((tile + 7) % 14);
    const float* inp = psfs + ((size_t)b * 2 + d) * PP;
    float lsum = 0.f;
    for (int idx = t; idx < 224 * 16; idx += 256) {
        int kh = idx >> 4, c = idx & 15;
        int skh = kh + 112; if (skh >= 224) skh -= 224;
        float diff = psf[kh * 17 + c] - inp[skh * PSZ + scol0 + c];
        lsum = fmaf(diff, diff, lsum);
    }
    red[t] = lsum;
    __syncthreads();
    for (int st = 128; st > 0; st >>= 1) {
        if (t < st) red[t] += red[t + st];
        __syncthreads();
    }
    if (t == 0)
        partials[(blockIdx.z * BB + blockIdx.y) * 14 + blockIdx.x] = red[0];
}

// ---------------- final ----------------
__global__ void k_final(const float* __restrict__ ws,
                        const float* __restrict__ partials,
                        float* __restrict__ out) {
    __shared__ float red[256];
    float s = 0.f;
    for (int i = threadIdx.x; i < N_PARTIALS; i += 256) s += partials[i];
    red[threadIdx.x] = s;
    __syncthreads();
    for (int st = 128; st > 0; st >>= 1) {
        if (threadIdx.x < st) red[threadIdx.x] += red[threadIdx.x + st];
        __syncthreads();
    }
    if (threadIdx.x == 0) {
        float recon = red[0] / (float)((size_t)BB * PP);
        out[0] = ws[1] + RECON_WEIGHT * recon;
    }
}

extern "C" void kernel_launch(void* const* d_in, const int* in_sizes, int n_in,
                              void* d_out, int out_size, void* d_ws, size_t ws_size,
                              hipStream_t stream) {
    const float* pred   = (const float*)d_in[0];
    const float* target = (const float*)d_in[1];
    const float* psfs   = (const float*)d_in[2];
    const float* zern   = (const float*)d_in[3];
    const float* mask   = (const float*)d_in[4];

    float*  ws       = (float*)d_ws;
    float*  phase    = ws + WS_PHASE_OFF;
    float*  partials = ws + WS_PHASE_OFF;   // aliases phase (dead after stage1)
    float2* T        = (float2*)(ws + WS_T_OFF);
    float*  out      = (float*)d_out;

    k_zloss<<<1, 256, 0, stream>>>(pred, target, ws);
    k_mask2<<<1, 256, 0, stream>>>(mask, ws);
    k_phase<<<dim3(PP / 256, BB / 16), 256, 0, stream>>>(pred, zern, mask, phase);
    k_stage1<<<dim3(14, BB, 2), 256, 0, stream>>>(phase, mask, T);
    k_stage2<<<dim3(14, BB, 2), 256, 0, stream>>>(T, psfs, ws, partials);
    k_final<<<1, 256, 0, stream>>>(ws, partials, out);
}

// Round 3
// 282.970 us; speedup vs baseline: 4.9432x; 1.3335x over previous
//
#include <hip/hip_runtime.h>
#include <math.h>

#define BB 128
#define MM 35
#define PSZ 224
#define PP (PSZ*PSZ)          // 50176
#define SIGN_PENALTY 10.0f
#define RECON_WEIGHT 0.4f
#define DEFOCUS_RAD 1.0f
#define EPS_F 1e-8f
#define TWO_PI_F 6.2831853071795864769f

// CT factorization: 224 = 14*16.  n = 14*n2 + n1 (n1<14, n2<16); k = 16*k1 + k2.
// X[16k1+k2] = sum_n1 W14[n1*k1] * Wtw(n1*k2/224) * [ sum_n2 x[14n2+n1] * W16[n2*k2] ]
// KEY: inner-DFT thread n1 reads slots {14n2+n1} and writes slots {k2*14+n1} —
// the SAME exclusively-owned index set → in-place in xs, no Bb buffer, half the LDS.

// ws layout (floats):
//   [0] sum(mask^2)   [1] z_loss
//   [2048 ..) phase [B][P][P] — dead after stage1; partials alias it
//   [T_OFF ..) T [2][B][P][P] complex
#define WS_PHASE_OFF    2048
#define WS_T_OFF        (WS_PHASE_OFF + BB*PP)
#define N_PARTIALS      (14*BB*2)

static constexpr float W16R[16] = {
    1.0f, 0.9238795325f, 0.7071067812f, 0.3826834324f, 0.0f,
    -0.3826834324f, -0.7071067812f, -0.9238795325f, -1.0f,
    -0.9238795325f, -0.7071067812f, -0.3826834324f, 0.0f,
    0.3826834324f, 0.7071067812f, 0.9238795325f};
static constexpr float W16I[16] = {
    0.0f, -0.3826834324f, -0.7071067812f, -0.9238795325f, -1.0f,
    -0.9238795325f, -0.7071067812f, -0.3826834324f, 0.0f,
    0.3826834324f, 0.7071067812f, 0.9238795325f, 1.0f,
    0.9238795325f, 0.7071067812f, 0.3826834324f};
static constexpr float W14R[14] = {
    1.0f, 0.9009688679f, 0.6234898019f, 0.2225209340f, -0.2225209340f,
    -0.6234898019f, -0.9009688679f, -1.0f, -0.9009688679f,
    -0.6234898019f, -0.2225209340f, 0.2225209340f, 0.6234898019f,
    0.9009688679f};
static constexpr float W14I[14] = {
    0.0f, -0.4338837391f, -0.7818314825f, -0.9749279122f, -0.9749279122f,
    -0.7818314825f, -0.4338837391f, 0.0f, 0.4338837391f,
    0.7818314825f, 0.9749279122f, 0.9749279122f, 0.7818314825f,
    0.4338837391f};

__device__ __forceinline__ float lincoord(int i) {
    return -1.0f + 2.0f * (float)i / (float)(PSZ - 1);
}

// ---------------- z_loss (block 0) + sum(mask^2) (block 1) ----------------
__global__ void k_small(const float* __restrict__ pred,
                        const float* __restrict__ target,
                        const float* __restrict__ mask,
                        float* __restrict__ ws) {
    __shared__ float red[256];
    float s = 0.f;
    if (blockIdx.x == 0) {
        for (int i = threadIdx.x; i < BB * MM; i += 256) {
            float p = pred[i], t = target[i];
            float d = p - t;
            float w = (p * t < 0.f) ? SIGN_PENALTY : 1.f;
            s = fmaf(d * d, w, s);
        }
    } else {
        for (int i = threadIdx.x; i < PP; i += 256) {
            float m = mask[i];
            s = fmaf(m, m, s);
        }
    }
    red[threadIdx.x] = s;
    __syncthreads();
    for (int st = 128; st > 0; st >>= 1) {
        if (threadIdx.x < st) red[threadIdx.x] += red[threadIdx.x + st];
        __syncthreads();
    }
    if (threadIdx.x == 0) {
        if (blockIdx.x == 0) ws[1] = red[0] / (float)(BB * MM);
        else                 ws[0] = red[0];
    }
}

// ---------------- phase = (pred @ zern) * mask ----------------
__global__ __launch_bounds__(256) void k_phase(const float* __restrict__ pred,
                                               const float* __restrict__ zern,
                                               const float* __restrict__ mask,
                                               float* __restrict__ phase) {
    __shared__ float pl[16 * MM];
    int bg = blockIdx.y;
    for (int i = threadIdx.x; i < 16 * MM; i += 256) {
        int j = i / MM, m = i % MM;
        pl[i] = pred[(bg * 16 + j) * MM + m];
    }
    __syncthreads();
    int pix = blockIdx.x * 256 + threadIdx.x;
    float acc[16];
#pragma unroll
    for (int j = 0; j < 16; j++) acc[j] = 0.f;
    for (int m = 0; m < MM; m++) {
        float z = zern[m * PP + pix];
#pragma unroll
        for (int j = 0; j < 16; j++) acc[j] = fmaf(pl[j * MM + m], z, acc[j]);
    }
    float mk = mask[pix];
#pragma unroll
    for (int j = 0; j < 16; j++) phase[(size_t)(bg * 16 + j) * PP + pix] = acc[j] * mk;
}

// ---------------- stage 1: row DFTs via CT 14x16, in-place LDS ----------------
// grid (14, B, 2): block handles 16 h-rows of one image. block = 256.
// LDS: xs [16 rows][225 complex] = 28800 B only.
__global__ __launch_bounds__(256) void k_stage1(const float* __restrict__ phase,
                                                const float* __restrict__ mask,
                                                float2* __restrict__ T) {
    __shared__ float xs[16 * 450];
    int h0 = blockIdx.x * 16;
    int b = blockIdx.y, d = blockIdx.z;
    int t = threadIdx.x;

    const float* ph_base = phase + (size_t)b * PP + (size_t)h0 * PSZ;
    for (int idx = t; idx < 16 * PSZ; idx += 256) {
        int r = idx / PSZ, w = idx - r * PSZ;
        float ph = ph_base[r * PSZ + w];
        if (d) {
            float vy = lincoord(h0 + r), vx = lincoord(w);
            ph += DEFOCUS_RAD * (2.f * (vx * vx + vy * vy) - 1.f);
        }
        float mk = mask[(h0 + r) * PSZ + w];
        float sn, cs;
        sincosf(ph, &sn, &cs);
        xs[r * 450 + 2 * w]     = mk * cs;
        xs[r * 450 + 2 * w + 1] = mk * sn;
    }
    __syncthreads();

    if (t < 224) {                    // 16 rows x 14 n1
        int r = t / 14, n1 = t - r * 14;
        float2* xr = (float2*)(xs + r * 450);
        float2 x[16];
#pragma unroll
        for (int n2 = 0; n2 < 16; n2++) x[n2] = xr[14 * n2 + n1];
        float stw_s, stw_c;
        sincosf(-TWO_PI_F * (float)n1 / 224.f, &stw_s, &stw_c);
        float twc = 1.f, tws = 0.f;
#pragma unroll
        for (int k2 = 0; k2 < 16; k2++) {
            float ar = 0.f, ai = 0.f;
#pragma unroll
            for (int n2 = 0; n2 < 16; n2++) {
                const float wr = W16R[(n2 * k2) & 15], wi = W16I[(n2 * k2) & 15];
                ar = fmaf(x[n2].x, wr, ar); ar = fmaf(-x[n2].y, wi, ar);
                ai = fmaf(x[n2].x, wi, ai); ai = fmaf(x[n2].y, wr, ai);
            }
            float br = ar * twc - ai * tws;
            float bi = ar * tws + ai * twc;
            xr[k2 * 14 + n1] = make_float2(br, bi);   // in-place: same owned slots
            float ntc = fmaf(twc, stw_c, -tws * stw_s);
            float nts = fmaf(twc, stw_s,  tws * stw_c);
            twc = ntc; tws = nts;
        }
    }
    __syncthreads();

    {                                 // 16 rows x 16 k2
        int r = t >> 4, k2 = t & 15;
        const float2* xr = (const float2*)(xs + r * 450);
        float2 Bt[14];
#pragma unroll
        for (int n1 = 0; n1 < 14; n1++) Bt[n1] = xr[k2 * 14 + n1];
        int img = d * BB + b;
        float2* Trow = T + ((size_t)img * PSZ + (h0 + r)) * PSZ;
#pragma unroll
        for (int k1 = 0; k1 < 14; k1++) {
            float ar = 0.f, ai = 0.f;
#pragma unroll
            for (int n1 = 0; n1 < 14; n1++) {
                const float wr = W14R[(n1 * k1) % 14], wi = W14I[(n1 * k1) % 14];
                ar = fmaf(Bt[n1].x, wr, ar); ar = fmaf(-Bt[n1].y, wi, ar);
                ai = fmaf(Bt[n1].x, wi, ai); ai = fmaf(Bt[n1].y, wr, ai);
            }
            Trow[16 * k1 + k2] = make_float2(ar, ai);
        }
    }
}

// ---------------- stage 2: column DFTs via CT 14x16 (in-place) + psf + loss ----
// grid (14, B, 2): block handles 16 columns of one image.
// LDS: xs [224 h][16 cols complex, stride 34 floats] = 30464 B; psf aliases xs.
__global__ __launch_bounds__(256) void k_stage2(const float2* __restrict__ T,
                                                const float* __restrict__ psfs,
                                                const float* __restrict__ ws,
                                                float* __restrict__ partials) {
    __shared__ float xs[224 * 34];
    __shared__ float red[256];
    float* psf = xs;   // aliases xs (B-values consumed into regs before psf writes)
    int tile = blockIdx.x, b = blockIdx.y, d = blockIdx.z;
    int img = d * BB + b;
    int col0 = tile * 16;
    int t = threadIdx.x;

    const float2* Tbase = T + (size_t)img * PP + col0;
    for (int idx = t; idx < 224 * 16; idx += 256) {
        int h = idx >> 4, c = idx & 15;
        float2 v = Tbase[(size_t)h * PSZ + c];
        xs[h * 34 + 2 * c]     = v.x;
        xs[h * 34 + 2 * c + 1] = v.y;
    }
    __syncthreads();

    if (t < 224) {                    // 14 n1 x 16 c
        int n1 = t >> 4, c = t & 15;
        float2 x[16];
#pragma unroll
        for (int n2 = 0; n2 < 16; n2++) {
            int h = 14 * n2 + n1;
            x[n2] = make_float2(xs[h * 34 + 2 * c], xs[h * 34 + 2 * c + 1]);
        }
        float stw_s, stw_c;
        sincosf(-TWO_PI_F * (float)n1 / 224.f, &stw_s, &stw_c);
        float twc = 1.f, tws = 0.f;
#pragma unroll
        for (int k2 = 0; k2 < 16; k2++) {
            float ar = 0.f, ai = 0.f;
#pragma unroll
            for (int n2 = 0; n2 < 16; n2++) {
                const float wr = W16R[(n2 * k2) & 15], wi = W16I[(n2 * k2) & 15];
                ar = fmaf(x[n2].x, wr, ar); ar = fmaf(-x[n2].y, wi, ar);
                ai = fmaf(x[n2].x, wi, ai); ai = fmaf(x[n2].y, wr, ai);
            }
            float br = ar * twc - ai * tws;
            float bi = ar * tws + ai * twc;
            int h = k2 * 14 + n1;     // in-place: same owned slots
            xs[h * 34 + 2 * c]     = br;
            xs[h * 34 + 2 * c + 1] = bi;
            float ntc = fmaf(twc, stw_c, -tws * stw_s);
            float nts = fmaf(twc, stw_s,  tws * stw_c);
            twc = ntc; tws = nts;
        }
    }
    __syncthreads();

    float denom = ws[0] * (float)PP + EPS_F;   // Parseval
    float inv_denom = 1.f / denom;
    float2 Bt[14];
    int k2 = t >> 4, c = t & 15;
#pragma unroll
    for (int n1 = 0; n1 < 14; n1++) {
        int h = k2 * 14 + n1;
        Bt[n1] = make_float2(xs[h * 34 + 2 * c], xs[h * 34 + 2 * c + 1]);
    }
    __syncthreads();   // ALL B-values in regs before psf writes clobber xs
#pragma unroll
    for (int k1 = 0; k1 < 14; k1++) {
        float ar = 0.f, ai = 0.f;
#pragma unroll
        for (int n1 = 0; n1 < 14; n1++) {
            const float wr = W14R[(n1 * k1) % 14], wi = W14I[(n1 * k1) % 14];
            ar = fmaf(Bt[n1].x, wr, ar); ar = fmaf(-Bt[n1].y, wi, ar);
            ai = fmaf(Bt[n1].x, wi, ai); ai = fmaf(Bt[n1].y, wr, ai);
        }
        int kh = 16 * k1 + k2;
        psf[kh * 17 + c] = fmaf(ar, ar, ai * ai) * inv_denom;
    }
    __syncthreads();

    int scol0 = 16 * ((tile + 7) % 14);
    const float* inp = psfs + ((size_t)b * 2 + d) * PP;
    float lsum = 0.f;
    for (int idx = t; idx < 224 * 16; idx += 256) {
        int kh = idx >> 4, cc = idx & 15;
        int skh = kh + 112; if (skh >= 224) skh -= 224;
        float diff = psf[kh * 17 + cc] - inp[skh * PSZ + scol0 + cc];
        lsum = fmaf(diff, diff, lsum);
    }
    red[t] = lsum;
    __syncthreads();
    for (int st = 128; st > 0; st >>= 1) {
        if (t < st) red[t] += red[t + st];
        __syncthreads();
    }
    if (t == 0)
        partials[(blockIdx.z * BB + blockIdx.y) * 14 + blockIdx.x] = red[0];
}

// ---------------- final ----------------
__global__ void k_final(const float* __restrict__ ws,
                        const float* __restrict__ partials,
                        float* __restrict__ out) {
    __shared__ float red[256];
    float s = 0.f;
    for (int i = threadIdx.x; i < N_PARTIALS; i += 256) s += partials[i];
    red[threadIdx.x] = s;
    __syncthreads();
    for (int st = 128; st > 0; st >>= 1) {
        if (threadIdx.x < st) red[threadIdx.x] += red[threadIdx.x + st];
        __syncthreads();
    }
    if (threadIdx.x == 0) {
        float recon = red[0] / (float)((size_t)BB * PP);
        out[0] = ws[1] + RECON_WEIGHT * recon;
    }
}

extern "C" void kernel_launch(void* const* d_in, const int* in_sizes, int n_in,
                              void* d_out, int out_size, void* d_ws, size_t ws_size,
                              hipStream_t stream) {
    const float* pred   = (const float*)d_in[0];
    const float* target = (const float*)d_in[1];
    const float* psfs   = (const float*)d_in[2];
    const float* zern   = (const float*)d_in[3];
    const float* mask   = (const float*)d_in[4];

    float*  ws       = (float*)d_ws;
    float*  phase    = ws + WS_PHASE_OFF;
    float*  partials = ws + WS_PHASE_OFF;   // aliases phase (dead after stage1)
    float2* T        = (float2*)(ws + WS_T_OFF);
    float*  out      = (float*)d_out;

    k_small<<<2, 256, 0, stream>>>(pred, target, mask, ws);
    k_phase<<<dim3(PP / 256, BB / 16), 256, 0, stream>>>(pred, zern, mask, phase);
    k_stage1<<<dim3(14, BB, 2), 256, 0, stream>>>(phase, mask, T);
    k_stage2<<<dim3(14, BB, 2), 256, 0, stream>>>(T, psfs, ws, partials);
    k_final<<<1, 256, 0, stream>>>(ws, partials, out);
}

// Round 4
// 231.271 us; speedup vs baseline: 6.0483x; 1.2235x over previous
//
#include <hip/hip_runtime.h>
#include <math.h>

#define BB 128
#define MM 35
#define PSZ 224
#define PP (PSZ*PSZ)          // 50176
#define SIGN_PENALTY 10.0f
#define RECON_WEIGHT 0.4f
#define DEFOCUS_RAD 1.0f
#define EPS_F 1e-8f
#define INV2PI 0.15915494309189535f

// CT factorization: 224 = 14*16.  n = 14*n2 + n1; k = 16*k1 + k2.
// Inner-DFT thread n1 owns slots {14n2+n1} == write slots {k2*14+n1} → in-place.
// Complex values packed bf16x2 in one dword (LDS and the T intermediate):
// halves LDS (→8 blocks/CU wave cap) and halves T HBM traffic.

// ws layout (floats):
//   [1] z_loss   [2..17] mask^2 partials (16 blocks)
//   [2048 ..) partials (stage2 block sums)
//   [T_OFF ..) T [2][B][P][P] packed bf16x2 (1 dword per complex)
#define WS_PART_OFF     2048
#define WS_T_OFF        (WS_PART_OFF + BB*PP)
#define N_PARTIALS      (14*BB*2)
#define S1 232            // stage1 LDS row stride (dwords); 232 % 32 == 8
#define S2 20             // stage2 LDS col-tile stride (dwords)

static constexpr float W16R[16] = {
    1.0f, 0.9238795325f, 0.7071067812f, 0.3826834324f, 0.0f,
    -0.3826834324f, -0.7071067812f, -0.9238795325f, -1.0f,
    -0.9238795325f, -0.7071067812f, -0.3826834324f, 0.0f,
    0.3826834324f, 0.7071067812f, 0.9238795325f};
static constexpr float W16I[16] = {
    0.0f, -0.3826834324f, -0.7071067812f, -0.9238795325f, -1.0f,
    -0.9238795325f, -0.7071067812f, -0.3826834324f, 0.0f,
    0.3826834324f, 0.7071067812f, 0.9238795325f, 1.0f,
    0.9238795325f, 0.7071067812f, 0.3826834324f};
static constexpr float W14R[14] = {
    1.0f, 0.9009688679f, 0.6234898019f, 0.2225209340f, -0.2225209340f,
    -0.6234898019f, -0.9009688679f, -1.0f, -0.9009688679f,
    -0.6234898019f, -0.2225209340f, 0.2225209340f, 0.6234898019f,
    0.9009688679f};
static constexpr float W14I[14] = {
    0.0f, -0.4338837391f, -0.7818314825f, -0.9749279122f, -0.9749279122f,
    -0.7818314825f, -0.4338837391f, 0.0f, 0.4338837391f,
    0.7818314825f, 0.9749279122f, 0.9749279122f, 0.7818314825f,
    0.4338837391f};

__device__ __forceinline__ float lincoord(int i) {
    return -1.0f + 2.0f * (float)i / (float)(PSZ - 1);
}
// fast sin/cos: arg in radians -> revolutions, v_fract, v_sin/v_cos
__device__ __forceinline__ void fast_sincos(float x, float* s, float* c) {
    float rv = x * INV2PI;
    rv -= floorf(rv);
    *s = __builtin_amdgcn_sinf(rv);
    *c = __builtin_amdgcn_cosf(rv);
}
// twiddle base exp(-2*pi*i*n1/224): exact revolutions
__device__ __forceinline__ void tw_sincos(int n1, float* s, float* c) {
    float rv = (float)n1 * (-1.0f / 224.0f);
    rv -= floorf(rv);
    *s = __builtin_amdgcn_sinf(rv);
    *c = __builtin_amdgcn_cosf(rv);
}
__device__ __forceinline__ unsigned pack_bf2(float a, float b) {
    unsigned ua = __float_as_uint(a), ub = __float_as_uint(b);
    ua += 0x7fffu + ((ua >> 16) & 1u);   // RTNE
    ub += 0x7fffu + ((ub >> 16) & 1u);
    return (ua >> 16) | (ub & 0xffff0000u);
}
__device__ __forceinline__ float2 unpack_bf2(unsigned v) {
    return make_float2(__uint_as_float(v << 16), __uint_as_float(v & 0xffff0000u));
}

// ---------------- k_small: blocks 0..15 mask^2 partials; block 16 z_loss ----
__global__ void k_small(const float* __restrict__ pred,
                        const float* __restrict__ target,
                        const float* __restrict__ mask,
                        float* __restrict__ ws) {
    __shared__ float red[256];
    float s = 0.f;
    int bid = blockIdx.x;
    if (bid == 16) {
        for (int i = threadIdx.x; i < BB * MM; i += 256) {
            float p = pred[i], t = target[i];
            float d = p - t;
            float w = (p * t < 0.f) ? SIGN_PENALTY : 1.f;
            s = fmaf(d * d, w, s);
        }
    } else {
        const float4* m4 = (const float4*)(mask + bid * (PP / 16));
        for (int i = threadIdx.x; i < PP / 64; i += 256) {   // 784 float4
            float4 v = m4[i];
            s = fmaf(v.x, v.x, s); s = fmaf(v.y, v.y, s);
            s = fmaf(v.z, v.z, s); s = fmaf(v.w, v.w, s);
        }
    }
    red[threadIdx.x] = s;
    __syncthreads();
    for (int st = 128; st > 0; st >>= 1) {
        if (threadIdx.x < st) red[threadIdx.x] += red[threadIdx.x + st];
        __syncthreads();
    }
    if (threadIdx.x == 0) {
        if (bid == 16) ws[1] = red[0] / (float)(BB * MM);
        else           ws[2 + bid] = red[0];
    }
}

// ---------------- phase = (pred @ zern) * mask ----------------
__global__ __launch_bounds__(256) void k_phase(const float* __restrict__ pred,
                                               const float* __restrict__ zern,
                                               const float* __restrict__ mask,
                                               float* __restrict__ phase) {
    __shared__ float pl[16 * MM];
    int bg = blockIdx.y;
    for (int i = threadIdx.x; i < 16 * MM; i += 256) {
        int j = i / MM, m = i % MM;
        pl[i] = pred[(bg * 16 + j) * MM + m];
    }
    __syncthreads();
    int pix = blockIdx.x * 256 + threadIdx.x;
    float acc[16];
#pragma unroll
    for (int j = 0; j < 16; j++) acc[j] = 0.f;
    for (int m = 0; m < MM; m++) {
        float z = zern[m * PP + pix];
#pragma unroll
        for (int j = 0; j < 16; j++) acc[j] = fmaf(pl[j * MM + m], z, acc[j]);
    }
    float mk = mask[pix];
#pragma unroll
    for (int j = 0; j < 16; j++) phase[(size_t)(bg * 16 + j) * PP + pix] = acc[j] * mk;
}

// ---------------- stage 1: row DFTs, CT 14x16, bf16-packed LDS, bf16 T ------
// grid (14, B, 2). LDS: 16 rows x S1 dwords = 14848 B -> 8 blocks/CU cap.
__global__ __launch_bounds__(256, 8) void k_stage1(const float* __restrict__ phase,
                                                   const float* __restrict__ mask,
                                                   unsigned* __restrict__ T) {
    __shared__ unsigned xs[16 * S1];
    int h0 = blockIdx.x * 16;
    int b = blockIdx.y, d = blockIdx.z;
    int t = threadIdx.x;

    const float* ph_base = phase + (size_t)b * PP + (size_t)h0 * PSZ;
    for (int idx = t; idx < 16 * PSZ; idx += 256) {
        int r = idx / PSZ, w = idx - r * PSZ;
        float ph = ph_base[r * PSZ + w];
        if (d) {
            float vy = lincoord(h0 + r), vx = lincoord(w);
            ph += DEFOCUS_RAD * (2.f * (vx * vx + vy * vy) - 1.f);
        }
        float mk = mask[(h0 + r) * PSZ + w];
        float sn, cs;
        fast_sincos(ph, &sn, &cs);
        xs[r * S1 + w] = pack_bf2(mk * cs, mk * sn);
    }
    __syncthreads();

    if (t < 224) {                    // 16 rows x 14 n1
        int r = t / 14, n1 = t - r * 14;
        unsigned* xr = xs + r * S1;
        float2 x[16];
#pragma unroll
        for (int n2 = 0; n2 < 16; n2++) x[n2] = unpack_bf2(xr[14 * n2 + n1]);
        float stw_s, stw_c;
        tw_sincos(n1, &stw_s, &stw_c);
        float twc = 1.f, tws = 0.f;
#pragma unroll
        for (int k2 = 0; k2 < 16; k2++) {
            float ar = 0.f, ai = 0.f;
#pragma unroll
            for (int n2 = 0; n2 < 16; n2++) {
                const float wr = W16R[(n2 * k2) & 15], wi = W16I[(n2 * k2) & 15];
                ar = fmaf(x[n2].x, wr, ar); ar = fmaf(-x[n2].y, wi, ar);
                ai = fmaf(x[n2].x, wi, ai); ai = fmaf(x[n2].y, wr, ai);
            }
            float br = ar * twc - ai * tws;
            float bi = ar * tws + ai * twc;
            xr[k2 * 14 + n1] = pack_bf2(br, bi);   // in-place: same owned slots
            float ntc = fmaf(twc, stw_c, -tws * stw_s);
            float nts = fmaf(twc, stw_s,  tws * stw_c);
            twc = ntc; tws = nts;
        }
    }
    __syncthreads();

    {                                 // 16 rows x 16 k2
        int r = t >> 4, k2 = t & 15;
        const unsigned* xr = xs + r * S1;
        float2 Bt[14];
#pragma unroll
        for (int n1 = 0; n1 < 14; n1++) Bt[n1] = unpack_bf2(xr[k2 * 14 + n1]);
        int img = d * BB + b;
        unsigned* Trow = T + ((size_t)img * PSZ + (h0 + r)) * PSZ;
#pragma unroll
        for (int k1 = 0; k1 < 14; k1++) {
            float ar = 0.f, ai = 0.f;
#pragma unroll
            for (int n1 = 0; n1 < 14; n1++) {
                const float wr = W14R[(n1 * k1) % 14], wi = W14I[(n1 * k1) % 14];
                ar = fmaf(Bt[n1].x, wr, ar); ar = fmaf(-Bt[n1].y, wi, ar);
                ai = fmaf(Bt[n1].x, wi, ai); ai = fmaf(Bt[n1].y, wr, ai);
            }
            Trow[16 * k1 + k2] = pack_bf2(ar, ai);
        }
    }
}

// ---------------- stage 2: column DFTs (in-place, bf16 LDS) + psf + loss ----
// grid (14, B, 2). LDS: 224 x S2 dwords = 17920 B + red -> 8 blocks/CU cap.
__global__ __launch_bounds__(256, 8) void k_stage2(const unsigned* __restrict__ T,
                                                   const float* __restrict__ psfs,
                                                   const float* __restrict__ ws,
                                                   float* __restrict__ partials) {
    __shared__ unsigned xs[224 * S2];
    __shared__ float red[256];
    int tile = blockIdx.x, b = blockIdx.y, d = blockIdx.z;
    int img = d * BB + b;
    int col0 = tile * 16;
    int t = threadIdx.x;

    const unsigned* Tbase = T + (size_t)img * PP + col0;
    for (int idx = t; idx < 224 * 16; idx += 256) {
        int h = idx >> 4, c = idx & 15;
        xs[h * S2 + c] = Tbase[(size_t)h * PSZ + c];
    }
    __syncthreads();

    if (t < 224) {                    // 14 n1 x 16 c
        int n1 = t >> 4, c = t & 15;
        float2 x[16];
#pragma unroll
        for (int n2 = 0; n2 < 16; n2++) x[n2] = unpack_bf2(xs[(14 * n2 + n1) * S2 + c]);
        float stw_s, stw_c;
        tw_sincos(n1, &stw_s, &stw_c);
        float twc = 1.f, tws = 0.f;
#pragma unroll
        for (int k2 = 0; k2 < 16; k2++) {
            float ar = 0.f, ai = 0.f;
#pragma unroll
            for (int n2 = 0; n2 < 16; n2++) {
                const float wr = W16R[(n2 * k2) & 15], wi = W16I[(n2 * k2) & 15];
                ar = fmaf(x[n2].x, wr, ar); ar = fmaf(-x[n2].y, wi, ar);
                ai = fmaf(x[n2].x, wi, ai); ai = fmaf(x[n2].y, wr, ai);
            }
            float br = ar * twc - ai * tws;
            float bi = ar * tws + ai * twc;
            xs[(k2 * 14 + n1) * S2 + c] = pack_bf2(br, bi);  // in-place
            float ntc = fmaf(twc, stw_c, -tws * stw_s);
            float nts = fmaf(twc, stw_s,  tws * stw_c);
            twc = ntc; tws = nts;
        }
    }
    __syncthreads();

    float m2 = 0.f;
#pragma unroll
    for (int i = 0; i < 16; i++) m2 += ws[2 + i];      // uniform scalar loads
    float inv_denom = 1.f / (m2 * (float)PP + EPS_F);  // Parseval denominator

    int k2 = t >> 4, c = t & 15;
    float2 Bt[14];
#pragma unroll
    for (int n1 = 0; n1 < 14; n1++) Bt[n1] = unpack_bf2(xs[(k2 * 14 + n1) * S2 + c]);
    __syncthreads();   // ALL B-values in regs before psf writes clobber xs
#pragma unroll
    for (int k1 = 0; k1 < 14; k1++) {
        float ar = 0.f, ai = 0.f;
#pragma unroll
        for (int n1 = 0; n1 < 14; n1++) {
            const float wr = W14R[(n1 * k1) % 14], wi = W14I[(n1 * k1) % 14];
            ar = fmaf(Bt[n1].x, wr, ar); ar = fmaf(-Bt[n1].y, wi, ar);
            ai = fmaf(Bt[n1].x, wi, ai); ai = fmaf(Bt[n1].y, wr, ai);
        }
        int kh = 16 * k1 + k2;
        xs[kh * S2 + c] = __float_as_uint(fmaf(ar, ar, ai * ai) * inv_denom);
    }
    __syncthreads();

    int scol0 = 16 * ((tile + 7) % 14);
    const float* inp = psfs + ((size_t)b * 2 + d) * PP;
    float lsum = 0.f;
    for (int idx = t; idx < 224 * 16; idx += 256) {
        int kh = idx >> 4, cc = idx & 15;
        int skh = kh + 112; if (skh >= 224) skh -= 224;
        float diff = __uint_as_float(xs[kh * S2 + cc]) - inp[skh * PSZ + scol0 + cc];
        lsum = fmaf(diff, diff, lsum);
    }
    red[t] = lsum;
    __syncthreads();
    for (int st = 128; st > 0; st >>= 1) {
        if (t < st) red[t] += red[t + st];
        __syncthreads();
    }
    if (t == 0)
        partials[(blockIdx.z * BB + blockIdx.y) * 14 + blockIdx.x] = red[0];
}

// ---------------- final ----------------
__global__ void k_final(const float* __restrict__ ws,
                        const float* __restrict__ partials,
                        float* __restrict__ out) {
    __shared__ float red[256];
    float s = 0.f;
    for (int i = threadIdx.x; i < N_PARTIALS; i += 256) s += partials[i];
    red[threadIdx.x] = s;
    __syncthreads();
    for (int st = 128; st > 0; st >>= 1) {
        if (threadIdx.x < st) red[threadIdx.x] += red[threadIdx.x + st];
        __syncthreads();
    }
    if (threadIdx.x == 0) {
        float recon = red[0] / (float)((size_t)BB * PP);
        out[0] = ws[1] + RECON_WEIGHT * recon;
    }
}

extern "C" void kernel_launch(void* const* d_in, const int* in_sizes, int n_in,
                              void* d_out, int out_size, void* d_ws, size_t ws_size,
                              hipStream_t stream) {
    const float* pred   = (const float*)d_in[0];
    const float* target = (const float*)d_in[1];
    const float* psfs   = (const float*)d_in[2];
    const float* zern   = (const float*)d_in[3];
    const float* mask   = (const float*)d_in[4];

    float*    ws       = (float*)d_ws;
    float*    partials = ws + WS_PART_OFF;
    float*    phase    = ws + WS_PART_OFF;   // phase aliases partials (phase dead first)
    unsigned* T        = (unsigned*)(ws + WS_T_OFF);
    float*    out      = (float*)d_out;

    k_small<<<17, 256, 0, stream>>>(pred, target, mask, ws);
    k_phase<<<dim3(PP / 256, BB / 16), 256, 0, stream>>>(pred, zern, mask, phase);
    k_stage1<<<dim3(14, BB, 2), 256, 0, stream>>>(phase, mask, T);
    k_stage2<<<dim3(14, BB, 2), 256, 0, stream>>>(T, psfs, ws, partials);
    k_final<<<1, 256, 0, stream>>>(ws, partials, out);
}